// Round 10
// baseline (206.389 us; speedup 1.0000x reference)
//
#include <hip/hip_runtime.h>

// CapsNet conv + dynamic routing (MI355X / gfx950).
// R10: 512-thread blocks (8 waves), 2 blocks co-resident per CU.
//  - votes held PACKED bf16 in 64 VGPRs: pv[p][tf][ti2][rp], wave covers 64f x 128i
//  - conv in 4 i-subpasses (acc[4][2] f32 = 32 regs) -> pack after each pass
//  - W pre-converted to bf16[256][96] in d_ws by prep kernel (L2-resident),
//    fragments loaded straight from global; no wl in LDS -> LDS ~60 KB
//  - 2 blocks/CU x 8 waves = 4 waves/SIMD @ <=128 regs (launch_bounds(512,4))
// Fallback (ws too small): verified R7 kernel (48.3 us).
//
// Lane decomposition (l = lane, q = l>>4, il = l&15), wave wid: wf=wid>>1, wi=wid&1:
//   vote(i, f): i = wi*128 + p*32 + ti2*16 + il   (p in 0..3, ti2 in 0..1)
//               f = 64*wf + 16*tf + 4*q + r
//   c = 8*wf + 2*tf + (q>>1)   (capsule),  n = 4*(q&1) + r

#define BS 16
#define CI 256
#define CO 32
#define NO 8
#define HI 20
#define WI 20
#define HO 6
#define WO 6
#define NPIX 36
#define NTAP 81
#define XP 104          // xw k pitch (bf16)
#define KW 96           // wb k pitch (bf16)
#define NBLK 576

typedef __attribute__((ext_vector_type(8))) short bf16x8;
typedef __attribute__((ext_vector_type(4))) float f32x4;

__device__ __forceinline__ ushort f2bf(float x) {
    union { float f; unsigned u; } v; v.f = x;
    unsigned r = v.u + 0x7FFFu + ((v.u >> 16) & 1u);   // RNE
    return (ushort)(r >> 16);
}
__device__ __forceinline__ unsigned packbf(float a, float b) {
    return (unsigned)f2bf(a) | ((unsigned)f2bf(b) << 16);
}
__device__ __forceinline__ float bflo(unsigned u) { return __uint_as_float(u << 16); }
__device__ __forceinline__ float bfhi(unsigned u) { return __uint_as_float(u & 0xFFFF0000u); }

// ---- VALU cross-lane reductions (validated R7/R8) ----
template<int CTRL>
__device__ __forceinline__ float dpp_radd(float v) {
    int s = __builtin_amdgcn_update_dpp(0, __float_as_int(v), CTRL, 0xF, 0xF, true);
    return v + __int_as_float(s);
}
__device__ __forceinline__ float row16_sum_tail(float v) {
    v = dpp_radd<0x111>(v);   // row_shr:1
    v = dpp_radd<0x112>(v);   // row_shr:2
    v = dpp_radd<0x114>(v);   // row_shr:4
    v = dpp_radd<0x118>(v);   // row_shr:8
    return v;                 // lane 15 of each row holds the row sum
}
__device__ __forceinline__ float grp8_sum_all(float v) {
    v = dpp_radd<0xB1>(v);    // quad_perm xor1
    v = dpp_radd<0x4E>(v);    // quad_perm xor2
    v = dpp_radd<0x141>(v);   // row_half_mirror
    return v;
}
#if __has_builtin(__builtin_amdgcn_permlane16_swap)
typedef unsigned u32x2 __attribute__((ext_vector_type(2)));
__device__ __forceinline__ float xor16_sum(float v) {
    u32x2 r = __builtin_amdgcn_permlane16_swap(__float_as_uint(v), __float_as_uint(v), false, false);
    return __uint_as_float(r.x) + __uint_as_float(r.y);
}
#else
__device__ __forceinline__ float xor16_sum(float v) { return v + __shfl_xor(v, 16, 64); }
#endif
#if __has_builtin(__builtin_amdgcn_permlane32_swap)
typedef unsigned u32x2b __attribute__((ext_vector_type(2)));
__device__ __forceinline__ float xor32_sum(float v) {
    u32x2b r = __builtin_amdgcn_permlane32_swap(__float_as_uint(v), __float_as_uint(v), false, false);
    return __uint_as_float(r.x) + __uint_as_float(r.y);
}
#else
__device__ __forceinline__ float xor32_sum(float v) { return v + __shfl_xor(v, 32, 64); }
#endif

// ---------------- prep: W fp32[256][81] -> bf16[256][96] in ws ---------------
__global__ __launch_bounds__(256) void prep_w(const float* __restrict__ Wt,
                                              ushort* __restrict__ wb) {
    int idx = blockIdx.x * 256 + threadIdx.x;    // 96 blocks -> 24576
    int f = idx / KW, k = idx - f * KW;
    wb[idx] = (k < NTAP) ? f2bf(Wt[f * NTAP + k]) : (ushort)0;
}

// ---------------- main: 512 threads, 2 blocks/CU -----------------------------
__global__ __launch_bounds__(512, 4) void caps512_kernel(
    const ushort* __restrict__ wb,   // bf16 [256][96]
    const float* __restrict__ x,     // [16,256,1,20,20]
    const float* __restrict__ bias,  // [32,8,1,1]
    float* __restrict__ out)         // [16,32,8,6,6]
{
    __shared__ __align__(16) ushort xw[CI * XP];   // 53248 B
    __shared__ __align__(16) float  smx[4 * 256];  // softmax partials [wf][i]
    __shared__ __align__(16) float  pre[2 * 256];  // preact partials [wi][c*8+n]
    __shared__ __align__(16) float  act[256];      // activation broadcast

    const int t   = threadIdx.x, blk = blockIdx.x;
    const int b   = blk & 15;           // XCD-local image mapping
    const int hw  = blk >> 4;           // 0..35
    const int h   = hw / WO, w = hw % WO;
    const int w2  = 2 * w;
    const float* xb = x + b * CI * HI * WI;

    const int wid = t >> 6, l = t & 63;
    const int q = l >> 4, il = l & 15;
    const int wf = wid >> 1, wi = wid & 1;

    // ---- stage x window (coalesced float4 quads) + pads
    #pragma unroll
    for (int pass = 0; pass < 18; ++pass) {
        int idx = pass * 512 + t;            // 2304 rows x 4 quads
        int q4 = idx & 3, r = idx >> 2;
        int kh = r % 9, i = r / 9;
        float4 v = *(const float4*)(xb + (i * HI + 2 * h + kh) * WI + 4 * q4);
        const float* ve = &v.x;
        #pragma unroll
        for (int e = 0; e < 4; ++e) {
            int kw = 4 * q4 + e - w2;
            if ((unsigned)kw < 9u) xw[i * XP + kh * 9 + kw] = f2bf(ve[e]);
        }
    }
    if (w >= 4) {
        for (int r = t; r < CI * 9; r += 512) {
            int kh = r % 9, i = r / 9;
            float4 v = *(const float4*)(xb + (i * HI + 2 * h + kh) * WI + 16);
            const float* ve = &v.x;
            #pragma unroll
            for (int e = 0; e < 4; ++e) {
                int kw = 16 + e - w2;
                if ((unsigned)kw < 9u) xw[i * XP + kh * 9 + kw] = f2bf(ve[e]);
            }
        }
    }
    {   // zero-pad k in [81,104): 2 threads per row
        int i = t >> 1, s = t & 1;
        #pragma unroll
        for (int j = 0; j < 12; ++j) {
            int k = NTAP + s * 12 + j;
            if (k < XP) { xw[i * XP + k] = 0; xw[(i + 128) * XP + k] = 0; }
        }
    }

    const float bias_r = (t < 256) ? bias[t] : 0.f;
    __syncthreads();

    // ---- conv via MFMA in 4 i-subpasses; votes packed to bf16 pairs (over r)
    unsigned pv[4][4][2][2];   // [p][tf][ti2][rp]  = bf16x2{r=2rp, r=2rp+1}
    #pragma unroll
    for (int p = 0; p < 4; ++p) {
        f32x4 acc[4][2];
        #pragma unroll
        for (int tf = 0; tf < 4; ++tf)
            #pragma unroll
            for (int ti2 = 0; ti2 < 2; ++ti2)
                acc[tf][ti2] = (f32x4){0.f, 0.f, 0.f, 0.f};
        #pragma unroll
        for (int ks = 0; ks < 3; ++ks) {
            const int ko = ks * 32 + q * 8;
            bf16x8 af[4], bv[2];
            #pragma unroll
            for (int tf = 0; tf < 4; ++tf)
                af[tf] = *(const bf16x8*)&wb[(wf * 64 + tf * 16 + il) * KW + ko];
            #pragma unroll
            for (int ti2 = 0; ti2 < 2; ++ti2)
                bv[ti2] = *(const bf16x8*)&xw[(wi * 128 + p * 32 + ti2 * 16 + il) * XP + ko];
            #pragma unroll
            for (int tf = 0; tf < 4; ++tf)
                #pragma unroll
                for (int ti2 = 0; ti2 < 2; ++ti2)
                    acc[tf][ti2] = __builtin_amdgcn_mfma_f32_16x16x32_bf16(
                        af[tf], bv[ti2], acc[tf][ti2], 0, 0, 0);
        }
        #pragma unroll
        for (int tf = 0; tf < 4; ++tf)
            #pragma unroll
            for (int ti2 = 0; ti2 < 2; ++ti2) {
                pv[p][tf][ti2][0] = packbf(acc[tf][ti2][0], acc[tf][ti2][1]);
                pv[p][tf][ti2][1] = packbf(acc[tf][ti2][2], acc[tf][ti2][3]);
            }
    }

    // ---- dynamic routing, 3 iterations
    float lg[4][4][2];   // [tf][p][ti2]
    #pragma unroll
    for (int tf = 0; tf < 4; ++tf)
        #pragma unroll
        for (int p = 0; p < 4; ++p)
            #pragma unroll
            for (int ti2 = 0; ti2 < 2; ++ti2) lg[tf][p][ti2] = 0.f;

    #pragma unroll
    for (int it = 0; it < 3; ++it) {
        float pp[4][4];   // [tf][r]
        #pragma unroll
        for (int tf = 0; tf < 4; ++tf)
            #pragma unroll
            for (int r = 0; r < 4; ++r) pp[tf][r] = 0.f;

        if (it == 0) {
            // route uniform 1/32
            #pragma unroll
            for (int p = 0; p < 4; ++p)
                #pragma unroll
                for (int ti2 = 0; ti2 < 2; ++ti2)
                    #pragma unroll
                    for (int tf = 0; tf < 4; ++tf) {
                        unsigned u0 = pv[p][tf][ti2][0], u1 = pv[p][tf][ti2][1];
                        pp[tf][0] += bflo(u0); pp[tf][1] += bfhi(u0);
                        pp[tf][2] += bflo(u1); pp[tf][3] += bfhi(u1);
                    }
            #pragma unroll
            for (int tf = 0; tf < 4; ++tf)
                #pragma unroll
                for (int r = 0; r < 4; ++r) pp[tf][r] *= 0.03125f;
        } else {
            // softmax denominators
            float srow[4][2];
            #pragma unroll
            for (int p = 0; p < 4; ++p)
                #pragma unroll
                for (int ti2 = 0; ti2 < 2; ++ti2) {
                    float s = 0.f;
                    #pragma unroll
                    for (int tf = 0; tf < 4; ++tf) s += __expf(lg[tf][p][ti2]);
                    srow[p][ti2] = xor32_sum(s);   // other c-half (q>>1), VALU
                }
            if (q == 0) {
                #pragma unroll
                for (int p = 0; p < 4; ++p)
                    #pragma unroll
                    for (int ti2 = 0; ti2 < 2; ++ti2)
                        smx[wf * 256 + wi * 128 + p * 32 + ti2 * 16 + il] = srow[p][ti2];
            }
            __syncthreads();
            #pragma unroll
            for (int p = 0; p < 4; ++p)
                #pragma unroll
                for (int ti2 = 0; ti2 < 2; ++ti2) {
                    const int i = wi * 128 + p * 32 + ti2 * 16 + il;
                    const float rt = __builtin_amdgcn_rcpf(
                        smx[i] + smx[256 + i] + smx[512 + i] + smx[768 + i]);
                    #pragma unroll
                    for (int tf = 0; tf < 4; ++tf) {
                        const float route = __expf(lg[tf][p][ti2]) * rt;
                        unsigned u0 = pv[p][tf][ti2][0], u1 = pv[p][tf][ti2][1];
                        pp[tf][0] += route * bflo(u0); pp[tf][1] += route * bfhi(u0);
                        pp[tf][2] += route * bflo(u1); pp[tf][3] += route * bfhi(u1);
                    }
                }
        }

        // --- reduce over il (16 i-lanes) on the VALU pipe (DPP)
        #pragma unroll
        for (int tf = 0; tf < 4; ++tf)
            #pragma unroll
            for (int r = 0; r < 4; ++r)
                pp[tf][r] = row16_sum_tail(pp[tf][r]);
        if (il == 15) {
            #pragma unroll
            for (int tf = 0; tf < 4; ++tf) {
                int c = wf * 8 + tf * 2 + (q >> 1);
                f32x4 vv = {pp[tf][0], pp[tf][1], pp[tf][2], pp[tf][3]};
                *(f32x4*)&pre[wi * 256 + c * 8 + (q & 1) * 4] = vv;
            }
        }
        __syncthreads();

        // --- finish preact + squash (threads 0..255), broadcast act
        if (t < 256) {
            float s = bias_r + pre[t] + pre[256 + t];
            float sq = grp8_sum_all(s * s);
            float a = s * __builtin_amdgcn_sqrtf(sq) * __builtin_amdgcn_rcpf(1.f + sq);
            if (it == 2) {
                int c = t >> 3, n = t & 7;
                out[((b * CO + c) * NO + n) * NPIX + hw] = a;
            } else {
                act[t] = a;
            }
        }

        // --- distances -> logits (skip on last iter)
        if (it < 2) {
            __syncthreads();   // act ready
            #pragma unroll
            for (int tf = 0; tf < 4; ++tf) {
                const int c = wf * 8 + tf * 2 + (q >> 1);
                f32x4 av = *(const f32x4*)&act[c * 8 + (q & 1) * 4];
                #pragma unroll
                for (int p = 0; p < 4; ++p)
                    #pragma unroll
                    for (int ti2 = 0; ti2 < 2; ++ti2) {
                        unsigned u0 = pv[p][tf][ti2][0], u1 = pv[p][tf][ti2][1];
                        float d = bflo(u0) * av[0] + bfhi(u0) * av[1]
                                + bflo(u1) * av[2] + bfhi(u1) * av[3];
                        lg[tf][p][ti2] += xor16_sum(d);   // other n-half, VALU
                    }
            }
        }
    }
}

// ---------------- fallback: verified R7 kernel (1024 thr, 48.3 us) -----------
__global__ __launch_bounds__(1024) void caps_kernel_r7(
    const float* __restrict__ x, const float* __restrict__ Wt,
    const float* __restrict__ bias, float* __restrict__ out)
{
    __shared__ __align__(16) ushort xw[CI * XP];
    __shared__ __align__(16) ushort wl[CO * NO * XP];
    __shared__ __align__(16) float  smx[4 * 256];
    __shared__ __align__(16) float  pre[4 * 256];
    __shared__ __align__(16) float  act[256];

    const int t = threadIdx.x, blk = blockIdx.x;
    const int b = blk & 15, hw = blk >> 4;
    const int h = hw / WO, w = hw % WO, w2 = 2 * w;
    const int wid = t >> 6, l = t & 63, q = l >> 4, il = l & 15;
    const int wf = wid >> 2, wi = wid & 3;

    for (int p = t; p < CO * NO * NTAP; p += 1024) {
        int f = p / NTAP, k = p - f * NTAP;
        wl[f * XP + k] = f2bf(Wt[p]);
    }
    {
        int i = t >> 2, s4 = t & 3;
        #pragma unroll
        for (int j = 0; j < 6; ++j) {
            int k = NTAP + s4 * 6 + j;
            if (k < XP) { xw[i * XP + k] = 0; wl[i * XP + k] = 0; }
        }
    }
    #pragma unroll
    for (int pass = 0; pass < 9; ++pass) {
        int idx = pass * 1024 + t;
        int q4 = idx & 3, r = idx >> 2;
        int kh = r % 9, i = r / 9;
        float4 v = *(const float4*)(x + ((b * CI + i) * HI + (2 * h + kh)) * WI + 4 * q4);
        const float* ve = &v.x;
        #pragma unroll
        for (int e = 0; e < 4; ++e) {
            int kw = 4 * q4 + e - w2;
            if ((unsigned)kw < 9u) xw[i * XP + kh * 9 + kw] = f2bf(ve[e]);
        }
    }
    if (w >= 4) {
        for (int r = t; r < CI * 9; r += 1024) {
            int kh = r % 9, i = r / 9;
            float4 v = *(const float4*)(x + ((b * CI + i) * HI + (2 * h + kh)) * WI + 16);
            const float* ve = &v.x;
            #pragma unroll
            for (int e = 0; e < 4; ++e) {
                int kw = 16 + e - w2;
                if ((unsigned)kw < 9u) xw[i * XP + kh * 9 + kw] = f2bf(ve[e]);
            }
        }
    }
    const float bias_r = (t < 256) ? bias[t] : 0.f;
    __syncthreads();

    f32x4 acc[4][4];
    #pragma unroll
    for (int tf = 0; tf < 4; ++tf)
        #pragma unroll
        for (int ti = 0; ti < 4; ++ti) acc[tf][ti] = (f32x4){0.f, 0.f, 0.f, 0.f};
    #pragma unroll
    for (int ks = 0; ks < 3; ++ks) {
        const int ko = ks * 32 + q * 8;
        bf16x8 af[4], bv[4];
        #pragma unroll
        for (int tf = 0; tf < 4; ++tf)
            af[tf] = *(const bf16x8*)&wl[(wf * 64 + tf * 16 + il) * XP + ko];
        #pragma unroll
        for (int ti = 0; ti < 4; ++ti)
            bv[ti] = *(const bf16x8*)&xw[(wi * 64 + ti * 16 + il) * XP + ko];
        #pragma unroll
        for (int tf = 0; tf < 4; ++tf)
            #pragma unroll
            for (int ti = 0; ti < 4; ++ti)
                acc[tf][ti] = __builtin_amdgcn_mfma_f32_16x16x32_bf16(
                    af[tf], bv[ti], acc[tf][ti], 0, 0, 0);
    }

    float lg[4][4];
    #pragma unroll
    for (int tf = 0; tf < 4; ++tf)
        #pragma unroll
        for (int ti = 0; ti < 4; ++ti) lg[tf][ti] = 0.f;

    #pragma unroll
    for (int it = 0; it < 3; ++it) {
        float pp[4][4];
        if (it == 0) {
            #pragma unroll
            for (int tf = 0; tf < 4; ++tf)
                #pragma unroll
                for (int r = 0; r < 4; ++r)
                    pp[tf][r] = (acc[tf][0][r] + acc[tf][1][r]
                               + acc[tf][2][r] + acc[tf][3][r]) * 0.03125f;
        } else {
            float e[4][4], srow[4] = {0.f, 0.f, 0.f, 0.f};
            #pragma unroll
            for (int tf = 0; tf < 4; ++tf)
                #pragma unroll
                for (int ti = 0; ti < 4; ++ti) {
                    e[tf][ti] = __expf(lg[tf][ti]);
                    srow[ti] += e[tf][ti];
                }
            #pragma unroll
            for (int ti = 0; ti < 4; ++ti) srow[ti] = xor32_sum(srow[ti]);
            if (q == 0) {
                #pragma unroll
                for (int ti = 0; ti < 4; ++ti)
                    smx[wf * 256 + wi * 64 + ti * 16 + il] = srow[ti];
            }
            __syncthreads();
            float rtot[4];
            #pragma unroll
            for (int ti = 0; ti < 4; ++ti) {
                int i = wi * 64 + ti * 16 + il;
                rtot[ti] = __builtin_amdgcn_rcpf(
                    smx[i] + smx[256 + i] + smx[512 + i] + smx[768 + i]);
            }
            float route[4][4];
            #pragma unroll
            for (int tf = 0; tf < 4; ++tf)
                #pragma unroll
                for (int ti = 0; ti < 4; ++ti) route[tf][ti] = e[tf][ti] * rtot[ti];
            #pragma unroll
            for (int tf = 0; tf < 4; ++tf)
                #pragma unroll
                for (int r = 0; r < 4; ++r)
                    pp[tf][r] = route[tf][0] * acc[tf][0][r] + route[tf][1] * acc[tf][1][r]
                              + route[tf][2] * acc[tf][2][r] + route[tf][3] * acc[tf][3][r];
        }
        #pragma unroll
        for (int tf = 0; tf < 4; ++tf)
            #pragma unroll
            for (int r = 0; r < 4; ++r)
                pp[tf][r] = row16_sum_tail(pp[tf][r]);
        if (il == 15) {
            #pragma unroll
            for (int tf = 0; tf < 4; ++tf) {
                int c = wf * 8 + tf * 2 + (q >> 1);
                f32x4 vv = {pp[tf][0], pp[tf][1], pp[tf][2], pp[tf][3]};
                *(f32x4*)&pre[wi * 256 + c * 8 + (q & 1) * 4] = vv;
            }
        }
        __syncthreads();
        if (t < 256) {
            float s = bias_r + pre[t] + pre[256 + t] + pre[512 + t] + pre[768 + t];
            float sq = grp8_sum_all(s * s);
            float a = s * __builtin_amdgcn_sqrtf(sq) * __builtin_amdgcn_rcpf(1.f + sq);
            if (it == 2) {
                int c = t >> 3, n = t & 7;
                out[(((b * CO + c) * NO + n) * HO + h) * WO + w] = a;
            } else act[t] = a;
        }
        if (it < 2) {
            __syncthreads();
            #pragma unroll
            for (int tf = 0; tf < 4; ++tf) {
                int c = wf * 8 + tf * 2 + (q >> 1);
                f32x4 av = *(const f32x4*)&act[c * 8 + (q & 1) * 4];
                #pragma unroll
                for (int ti = 0; ti < 4; ++ti) {
                    float d = acc[tf][ti][0] * av[0] + acc[tf][ti][1] * av[1]
                            + acc[tf][ti][2] * av[2] + acc[tf][ti][3] * av[3];
                    lg[tf][ti] += xor16_sum(d);
                }
            }
        }
    }
}

extern "C" void kernel_launch(void* const* d_in, const int* in_sizes, int n_in,
                              void* d_out, int out_size, void* d_ws, size_t ws_size,
                              hipStream_t stream) {
    const float* x    = (const float*)d_in[0];
    const float* Wt   = (const float*)d_in[1];
    const float* bias = (const float*)d_in[2];
    float* out = (float*)d_out;

    if (ws_size >= (size_t)256 * KW * sizeof(ushort)) {
        ushort* wb = (ushort*)d_ws;
        prep_w<<<96, 256, 0, stream>>>(Wt, wb);
        caps512_kernel<<<NBLK, 512, 0, stream>>>(wb, x, bias, out);
    } else {
        caps_kernel_r7<<<NBLK, 1024, 0, stream>>>(x, Wt, bias, out);
    }
}

// Round 11
// 45.997 us; speedup vs baseline: 4.4870x; 4.4870x over previous
//
#include <hip/hip_runtime.h>

// CapsNet conv + dynamic routing, single fused kernel (MI355X / gfx950).
// R11 = R7 (verified 48.3 us, the only spill-free shape: 1024 thr, votes in
// 64-AGPR accumulator, <=64 VGPR routing state) +
//  (a) persistent blocks: grid=256, 2-3 pixels each; W/pads staged once;
//      next pixel's x staged right after conv with #pragma unroll 1 and a
//      single live float4 (fixes R9's hoisting spill),
//  (b) division-free W staging (f = t>>2 chunk layout),
//  (c) logits pre-scaled by log2e -> raw v_exp_f32 softmax.
//
// Lane decomposition (l = lane, q = l>>4, il = l&15), wave (wf, wi):
//   acc[tf][ti].r = votes[ i = 64*wi+16*ti+il ][ f = 64*wf+16*tf+4*q+r ]
//   c = 8*wf + 2*tf + (q>>1)   (capsule),  n = 4*(q&1) + r

#define BS 16
#define CI 256
#define CO 32
#define NO 8
#define HI 20
#define WI 20
#define HO 6
#define WO 6
#define NPIX 36
#define NTAP 81
#define XP 104          // k pitch (bf16), 2-way banks (free)
#define NBLK 256

typedef __attribute__((ext_vector_type(8))) short bf16x8;
typedef __attribute__((ext_vector_type(4))) float f32x4;

__device__ __forceinline__ ushort f2bf(float x) {
    union { float f; unsigned u; } v; v.f = x;
    unsigned r = v.u + 0x7FFFu + ((v.u >> 16) & 1u);   // RNE
    return (ushort)(r >> 16);
}

// ---- VALU cross-lane reductions (validated R7/R8) ----
template<int CTRL>
__device__ __forceinline__ float dpp_radd(float v) {
    int s = __builtin_amdgcn_update_dpp(0, __float_as_int(v), CTRL, 0xF, 0xF, true);
    return v + __int_as_float(s);
}
__device__ __forceinline__ float row16_sum_tail(float v) {
    v = dpp_radd<0x111>(v);   // row_shr:1
    v = dpp_radd<0x112>(v);   // row_shr:2
    v = dpp_radd<0x114>(v);   // row_shr:4
    v = dpp_radd<0x118>(v);   // row_shr:8
    return v;                 // lane 15 of each row holds the row sum
}
__device__ __forceinline__ float grp8_sum_all(float v) {
    v = dpp_radd<0xB1>(v);    // quad_perm xor1
    v = dpp_radd<0x4E>(v);    // quad_perm xor2
    v = dpp_radd<0x141>(v);   // row_half_mirror
    return v;
}
#if __has_builtin(__builtin_amdgcn_permlane16_swap)
typedef unsigned u32x2 __attribute__((ext_vector_type(2)));
__device__ __forceinline__ float xor16_sum(float v) {
    u32x2 r = __builtin_amdgcn_permlane16_swap(__float_as_uint(v), __float_as_uint(v), false, false);
    return __uint_as_float(r.x) + __uint_as_float(r.y);
}
#else
__device__ __forceinline__ float xor16_sum(float v) { return v + __shfl_xor(v, 16, 64); }
#endif
#if __has_builtin(__builtin_amdgcn_permlane32_swap)
typedef unsigned u32x2b __attribute__((ext_vector_type(2)));
__device__ __forceinline__ float xor32_sum(float v) {
    u32x2b r = __builtin_amdgcn_permlane32_swap(__float_as_uint(v), __float_as_uint(v), false, false);
    return __uint_as_float(r.x) + __uint_as_float(r.y);
}
#else
__device__ __forceinline__ float xor32_sum(float v) { return v + __shfl_xor(v, 32, 64); }
#endif

// exp2-based softmax when available: logits accumulate pre-scaled by log2(e)
#if __has_builtin(__builtin_amdgcn_exp2f)
#define EXPFN(x) __builtin_amdgcn_exp2f(x)
#define ASCALE 1.44269504f
#else
#define EXPFN(x) __expf(x)
#define ASCALE 1.0f
#endif

// lean x-window staging: one float4 live at a time (safe while acc is live)
__device__ __forceinline__ void stage_x(const float* __restrict__ xb,
                                        ushort* __restrict__ xw,
                                        int t, int h, int w) {
    const int w2 = 2 * w;
    #pragma unroll 1
    for (int idx = t; idx < CI * 9 * 4; idx += 1024) {
        int q4 = idx & 3, r = idx >> 2;
        int kh = r % 9, i = r / 9;
        float4 v = *(const float4*)(xb + (i * HI + 2 * h + kh) * WI + 4 * q4);
        const float* ve = &v.x;
        #pragma unroll
        for (int e = 0; e < 4; ++e) {
            int kw = 4 * q4 + e - w2;
            if ((unsigned)kw < 9u) xw[i * XP + kh * 9 + kw] = f2bf(ve[e]);
        }
    }
    if (w >= 4) {
        #pragma unroll 1
        for (int r = t; r < CI * 9; r += 1024) {
            int kh = r % 9, i = r / 9;
            float4 v = *(const float4*)(xb + (i * HI + 2 * h + kh) * WI + 16);
            const float* ve = &v.x;
            #pragma unroll
            for (int e = 0; e < 4; ++e) {
                int kw = 16 + e - w2;
                if ((unsigned)kw < 9u) xw[i * XP + kh * 9 + kw] = f2bf(ve[e]);
            }
        }
    }
}

__global__ __launch_bounds__(1024) void caps_kernel(
    const float* __restrict__ x,     // [16,256,1,20,20]
    const float* __restrict__ Wt,    // [256,1,9,9]
    const float* __restrict__ bias,  // [32,8,1,1]
    float* __restrict__ out)         // [16,32,8,6,6]
{
    __shared__ __align__(16) ushort xw[CI * XP];        // 53248 B
    __shared__ __align__(16) ushort wl[CO * NO * XP];   // 53248 B
    __shared__ __align__(16) float  smx[4 * 256];       // softmax partials [wf][i]
    __shared__ __align__(16) float  pre[4 * 256];       // preact partials [wi][c*8+n]
    __shared__ __align__(16) float  act[256];           // activation broadcast

    const int t   = threadIdx.x, blk = blockIdx.x;
    const int b   = blk & 15;                 // same image for all pixels (XCD-local)
    const int npix = (blk < 64) ? 3 : 2;      // 64*3 + 192*2 = 576 pixels
    const float* xb = x + b * CI * HI * WI;

    const int wid = t >> 6, l = t & 63;
    const int q = l >> 4, il = l & 15;
    const int wf = wid >> 2, wi = wid & 3;

    // ---- one-time W staging, division-free: f = t>>2, 20/21-elem chunk
    {
        const int f = t >> 2, c4 = t & 3, k0 = c4 * 20;
        const float* ws = Wt + f * NTAP + k0;
        ushort* wd = wl + f * XP + k0;
        #pragma unroll
        for (int j = 0; j < 20; ++j) wd[j] = f2bf(ws[j]);
        if (c4 == 3) wd[20] = f2bf(ws[20]);
    }
    // ---- zero pads k in [81,104) for both tiles (once; xw pads never overwritten)
    {
        int i = t >> 2, s4 = t & 3;
        #pragma unroll
        for (int j = 0; j < 6; ++j) {
            int k = NTAP + s4 * 6 + j;
            if (k < XP) { xw[i * XP + k] = 0; wl[i * XP + k] = 0; }
        }
    }
    // ---- pixel-0 x staging
    stage_x(xb, xw, t, (blk >> 4) / WO, (blk >> 4) % WO);

    const float bias_r = (t < 256) ? bias[t] : 0.f;

    for (int p = 0; p < npix; ++p) {
        const int hw = (blk + 256 * p) >> 4;     // 0..35, unique across blocks

        __syncthreads();   // staged x visible; prior routing's LDS reads done

        // ---- conv via MFMA: votes^T (R7-verified)
        f32x4 acc[4][4];
        #pragma unroll
        for (int tf = 0; tf < 4; ++tf)
            #pragma unroll
            for (int ti = 0; ti < 4; ++ti)
                acc[tf][ti] = (f32x4){0.f, 0.f, 0.f, 0.f};

        #pragma unroll
        for (int ks = 0; ks < 3; ++ks) {
            const int ko = ks * 32 + q * 8;
            bf16x8 af[4], bv[4];
            #pragma unroll
            for (int tf = 0; tf < 4; ++tf)
                af[tf] = *(const bf16x8*)&wl[(wf * 64 + tf * 16 + il) * XP + ko];
            #pragma unroll
            for (int ti = 0; ti < 4; ++ti)
                bv[ti] = *(const bf16x8*)&xw[(wi * 64 + ti * 16 + il) * XP + ko];
            #pragma unroll
            for (int tf = 0; tf < 4; ++tf)
                #pragma unroll
                for (int ti = 0; ti < 4; ++ti)
                    acc[tf][ti] = __builtin_amdgcn_mfma_f32_16x16x32_bf16(
                        af[tf], bv[ti], acc[tf][ti], 0, 0, 0);
        }

        __syncthreads();   // conv reads of xw complete -> xw free for restage

        // ---- lean-staged next pixel's x: latency hides under routing
        if (p + 1 < npix) {
            const int hwn = (blk + 256 * (p + 1)) >> 4;
            stage_x(xb, xw, t, hwn / WO, hwn % WO);
        }

        // ---- dynamic routing, 3 iterations (R7-verified algebra)
        float lg[4][4];
        #pragma unroll
        for (int tf = 0; tf < 4; ++tf)
            #pragma unroll
            for (int ti = 0; ti < 4; ++ti) lg[tf][ti] = 0.f;

        #pragma unroll
        for (int it = 0; it < 3; ++it) {
            // --- preact partials pp[tf][r]
            float pp[4][4];
            if (it == 0) {
                #pragma unroll
                for (int tf = 0; tf < 4; ++tf)
                    #pragma unroll
                    for (int r = 0; r < 4; ++r)
                        pp[tf][r] = (acc[tf][0][r] + acc[tf][1][r]
                                   + acc[tf][2][r] + acc[tf][3][r]) * 0.03125f;
            } else {
                float e[4][4], srow[4] = {0.f, 0.f, 0.f, 0.f};
                #pragma unroll
                for (int tf = 0; tf < 4; ++tf)
                    #pragma unroll
                    for (int ti = 0; ti < 4; ++ti) {
                        e[tf][ti] = EXPFN(lg[tf][ti]);
                        srow[ti] += e[tf][ti];
                    }
                #pragma unroll
                for (int ti = 0; ti < 4; ++ti)
                    srow[ti] = xor32_sum(srow[ti]);   // other c-half, VALU
                if (q == 0) {
                    #pragma unroll
                    for (int ti = 0; ti < 4; ++ti)
                        smx[wf * 256 + wi * 64 + ti * 16 + il] = srow[ti];
                }
                __syncthreads();
                float rtot[4];
                #pragma unroll
                for (int ti = 0; ti < 4; ++ti) {
                    int i = wi * 64 + ti * 16 + il;
                    rtot[ti] = __builtin_amdgcn_rcpf(
                        smx[i] + smx[256 + i] + smx[512 + i] + smx[768 + i]);
                }
                float route[4][4];
                #pragma unroll
                for (int tf = 0; tf < 4; ++tf)
                    #pragma unroll
                    for (int ti = 0; ti < 4; ++ti) route[tf][ti] = e[tf][ti] * rtot[ti];
                #pragma unroll
                for (int tf = 0; tf < 4; ++tf)
                    #pragma unroll
                    for (int r = 0; r < 4; ++r)
                        pp[tf][r] = route[tf][0] * acc[tf][0][r] + route[tf][1] * acc[tf][1][r]
                                  + route[tf][2] * acc[tf][2][r] + route[tf][3] * acc[tf][3][r];
            }

            // --- reduce over il (16 i-lanes) on the VALU pipe (DPP)
            #pragma unroll
            for (int tf = 0; tf < 4; ++tf)
                #pragma unroll
                for (int r = 0; r < 4; ++r)
                    pp[tf][r] = row16_sum_tail(pp[tf][r]);
            if (il == 15) {
                #pragma unroll
                for (int tf = 0; tf < 4; ++tf) {
                    int c = wf * 8 + tf * 2 + (q >> 1);
                    f32x4 vv = {pp[tf][0], pp[tf][1], pp[tf][2], pp[tf][3]};
                    *(f32x4*)&pre[wi * 256 + c * 8 + (q & 1) * 4] = vv;
                }
            }
            __syncthreads();

            // --- finish preact + squash (threads 0..255), broadcast act
            if (t < 256) {
                float s = bias_r + pre[t] + pre[256 + t] + pre[512 + t] + pre[768 + t];
                float sq = grp8_sum_all(s * s);       // sum over 8 n-lanes (DPP)
                float a = s * __builtin_amdgcn_sqrtf(sq) * __builtin_amdgcn_rcpf(1.f + sq);
                if (it == 2) {
                    int c = t >> 3, n = t & 7;
                    out[((b * CO + c) * NO + n) * NPIX + hw] = a;
                } else {
                    act[t] = a * ASCALE;   // pre-scale by log2(e) for exp2 softmax
                }
            }

            // --- distances -> logits (skip on last iter)
            if (it < 2) {
                __syncthreads();   // act ready
                #pragma unroll
                for (int tf = 0; tf < 4; ++tf) {
                    int c = wf * 8 + tf * 2 + (q >> 1);
                    f32x4 av = *(const f32x4*)&act[c * 8 + (q & 1) * 4];
                    #pragma unroll
                    for (int ti = 0; ti < 4; ++ti) {
                        float d = acc[tf][ti][0] * av[0] + acc[tf][ti][1] * av[1]
                                + acc[tf][ti][2] * av[2] + acc[tf][ti][3] * av[3];
                        lg[tf][ti] += xor16_sum(d);   // other n-half, VALU
                    }
                }
            }
        }
    }
}

extern "C" void kernel_launch(void* const* d_in, const int* in_sizes, int n_in,
                              void* d_out, int out_size, void* d_ws, size_t ws_size,
                              hipStream_t stream) {
    const float* x    = (const float*)d_in[0];
    const float* Wt   = (const float*)d_in[1];
    const float* bias = (const float*)d_in[2];
    float* out = (float*)d_out;
    caps_kernel<<<NBLK, 1024, 0, stream>>>(x, Wt, bias, out);
}